// Round 8
// baseline (8373.253 us; speedup 1.0000x reference)
//
#include <hip/hip_runtime.h>

#define S      4097              // states
#define KP     4160              // padded K: 130 blocks of 32; 520 uint4/row (mult of 8)
#define NBLK   256
#define NTHR   1024
#define PAIRS  4097              // (val,tag) i32x2 pairs per fs buffer

typedef int   i32x4  __attribute__((ext_vector_type(4)));
typedef int   i32x2v __attribute__((ext_vector_type(2)));
typedef float f32x4  __attribute__((ext_vector_type(4)));
typedef short bf16x8 __attribute__((ext_vector_type(8)));

__device__ __forceinline__ float blo(unsigned int u) { return __uint_as_float(u << 16); }
__device__ __forceinline__ float bhi(unsigned int u) { return __uint_as_float(u & 0xffff0000u); }
__device__ __forceinline__ unsigned short rne_bf16(float x) {
  unsigned u = __float_as_uint(x);
  return (unsigned short)((u + 0x7fffu + ((u >> 16) & 1u)) >> 16);
}

__global__ void __launch_bounds__(NTHR) hmm_persist(
    const float* __restrict__ log_pi, const float* __restrict__ log_trans,
    const float* __restrict__ log_em, const int* __restrict__ obvs,
    i32x2v* __restrict__ pairs, int T)
{
  __shared__ __align__(16) unsigned short plds[17 * KP];  // P^T bf16, XOR-swizzled rows
  __shared__ __align__(16) unsigned short vb[KP];         // v bf16 (linear)
  __shared__ __align__(16) float part[8][256];            // MFMA partials
  __shared__ float red[16];
  __shared__ float em_lds[17];
  __shared__ float part2[8];

  const int tid = threadIdx.x, lane = tid & 63, wid = tid >> 6;
  const int b = blockIdx.x, jb = b * 16;
  const int ncols = (b == NBLK - 1) ? 17 : 16;

  // ---- one-time: stage P^T tile as bf16, zero-padded to KP, XOR-swizzled:
  //      element (r,k) -> uint4 slot (k>>3)^(r&7) within row r (bijective per row) ----
  for (int idx = tid; idx < ncols * KP; idx += NTHR) {
    int k = idx / ncols, r = idx - k * ncols;
    float p = (k < S) ? __expf(log_trans[(size_t)k * S + (jb + r)]) : 0.f;
    plds[r * KP + ((((k >> 3) ^ (r & 7)) << 3) | (k & 7))] = rne_bf16(p);
  }
  if (tid < KP - S) vb[S + tid] = 0;                      // static v padding (4097..4159)
  __syncthreads();

  for (int t = 0; t < T; ++t) {
    const i32x2v* pin  = pairs + ((t + 1) & 1) * PAIRS;   // tags == t when fresh
    i32x2v*       pout = pairs + (t & 1) * PAIRS;
    const int     obs  = obvs[t];

    // wave 15: issue em gather early (latency hides under poll)
    float emv = 0.f;
    if (wid == 15 && lane < ncols) emv = log_em[(size_t)(jb + lane) * S + obs];

    // ---- phase A: fused barrier+broadcast — fp32 (val,tag) poll ----
    float va0, va1, va2, va3, va4 = -3.4e38f;
    if (t == 0) {
      const float4 v4 = *(const float4*)(log_pi + 4 * tid);
      va0 = v4.x; va1 = v4.y; va2 = v4.z; va3 = v4.w;
      if (tid == 0) va4 = log_pi[4096];
    } else {
      const i32x2v* pa = pin + 4 * tid;
      const i32x2v* pb = pa + 2;
      const i32x2v* pt = pin + 4096;
      i32x4 A, B; i32x2v Tl;
      for (;;) {
        asm volatile("global_load_dwordx4 %0, %2, off sc0 sc1\n\t"
                     "global_load_dwordx4 %1, %3, off sc0 sc1"
                     : "=&v"(A), "=&v"(B) : "v"(pa), "v"(pb) : "memory");
        if (tid == 0)
          asm volatile("global_load_dwordx2 %0, %1, off sc0 sc1"
                       : "=&v"(Tl) : "v"(pt) : "memory");
        asm volatile("s_waitcnt vmcnt(0)" ::: "memory");
        __builtin_amdgcn_sched_barrier(0);
        bool ok = (A.y >= t) & (A.w >= t) & (B.y >= t) & (B.w >= t);
        if (tid == 0) ok &= (Tl.y >= t);
        if (ok) {
          va0 = __int_as_float(A.x); va1 = __int_as_float(A.z);
          va2 = __int_as_float(B.x); va3 = __int_as_float(B.z);
          if (tid == 0) va4 = __int_as_float(Tl.x);
          break;
        }
        __builtin_amdgcn_s_sleep(8);
      }
    }

    // block-wide max (red[lane&15] + shfl tree)
    float rmx = fmaxf(fmaxf(va0, va1), fmaxf(fmaxf(va2, va3), va4));
    #pragma unroll
    for (int off = 32; off; off >>= 1) rmx = fmaxf(rmx, __shfl_xor(rmx, off, 64));
    if (lane == 0) red[wid] = rmx;
    __syncthreads();
    float m = red[lane & 15];
    #pragma unroll
    for (int off = 8; off; off >>= 1) m = fmaxf(m, __shfl_xor(m, off, 64));

    // v = exp(va - m) -> bf16 (software RNE)
    float v0 = __expf(va0 - m), v1 = __expf(va1 - m);
    float v2 = __expf(va2 - m), v3 = __expf(va3 - m);
    unsigned b0 = rne_bf16(v0), b1 = rne_bf16(v1);
    unsigned b2 = rne_bf16(v2), b3 = rne_bf16(v3);
    *(int2*)(vb + 4 * tid) = make_int2((int)((b1 << 16) | b0), (int)((b3 << 16) | b2));
    if (tid == 0)
      *(int*)(vb + 4096) = (int)rne_bf16(__expf(va4 - m));  // [4096]=v4, [4097]=0
    if (wid == 15 && lane < ncols) em_lds[lane] = emv;
    __syncthreads();

    // ---- phase B: MFMA. A-read applies the row XOR -> conflict-free (2-way max) ----
    if (wid < 8) {
      const int kb0 = wid * 16, kbn = (wid == 7) ? 17 : 16;   // 129 real K-blocks
      const int r = lane & 15, r7 = r & 7;
      const uint4* ap = ((const uint4*)plds) + r * (KP / 8);
      const uint4* vp = (const uint4*)vb;
      const int g = lane >> 4;
      f32x4 accA = {0.f, 0.f, 0.f, 0.f}, accB = {0.f, 0.f, 0.f, 0.f};
      for (int mm = kb0; mm + 1 < kb0 + kbn; mm += 2) {
        bf16x8 a0 = __builtin_bit_cast(bf16x8, ap[(mm * 4 + g) ^ r7]);
        bf16x8 w0 = __builtin_bit_cast(bf16x8, vp[mm * 4 + g]);
        accA = __builtin_amdgcn_mfma_f32_16x16x32_bf16(a0, w0, accA, 0, 0, 0);
        bf16x8 a1 = __builtin_bit_cast(bf16x8, ap[((mm + 1) * 4 + g) ^ r7]);
        bf16x8 w1 = __builtin_bit_cast(bf16x8, vp[(mm + 1) * 4 + g]);
        accB = __builtin_amdgcn_mfma_f32_16x16x32_bf16(a1, w1, accB, 0, 0, 0);
      }
      if (kbn & 1) {
        int mm = kb0 + kbn - 1;
        bf16x8 a0 = __builtin_bit_cast(bf16x8, ap[(mm * 4 + g) ^ r7]);
        bf16x8 w0 = __builtin_bit_cast(bf16x8, vp[mm * 4 + g]);
        accA = __builtin_amdgcn_mfma_f32_16x16x32_bf16(a0, w0, accA, 0, 0, 0);
      }
      accA += accB;
      *(f32x4*)&part[wid][lane * 4] = accA;
    } else if (b == NBLK - 1) {
      // waves 8-15: column 16 (state 4096). Row 16: 16&7==0 -> unswizzled, linear.
      float a16 = 0.f;
      const uint4* prow = (const uint4*)(plds + 16 * KP);
      const uint4* vp   = (const uint4*)vb;
      for (int ot = (wid - 8) * 64 + lane; ot < KP / 8; ot += 512) {
        uint4 pw = prow[ot], vw = vp[ot];
        a16 += blo(pw.x) * blo(vw.x) + bhi(pw.x) * bhi(vw.x);
        a16 += blo(pw.y) * blo(vw.y) + bhi(pw.y) * bhi(vw.y);
        a16 += blo(pw.z) * blo(vw.z) + bhi(pw.z) * bhi(vw.z);
        a16 += blo(pw.w) * blo(vw.w) + bhi(pw.w) * bhi(vw.w);
      }
      #pragma unroll
      for (int off = 32; off; off >>= 1) a16 += __shfl_xor(a16, off, 64);
      if (lane == 0) part2[wid - 8] = a16;
    }
    __syncthreads();

    // ---- finalize + publish (wave 15): fs_new = em + m + log(dot) ----
    const int tag = t + 1;
    if (wid == 15) {
      f32x4 tot = {0.f, 0.f, 0.f, 0.f};
      #pragma unroll
      for (int p = 0; p < 8; ++p) tot += *(const f32x4*)&part[p][lane * 4];
      if ((lane & 15) == 0) {                  // lanes 0,16,32,48: rows 4g..4g+3 (col 0)
        const int j0 = (lane >> 4) * 4;
        float r0 = em_lds[j0 + 0] + m + __logf(tot.x);
        float r1 = em_lds[j0 + 1] + m + __logf(tot.y);
        float r2 = em_lds[j0 + 2] + m + __logf(tot.z);
        float r3 = em_lds[j0 + 3] + m + __logf(tot.w);
        i32x4 o1, o2;
        o1.x = __float_as_int(r0); o1.y = tag; o1.z = __float_as_int(r1); o1.w = tag;
        o2.x = __float_as_int(r2); o2.y = tag; o2.z = __float_as_int(r3); o2.w = tag;
        const i32x2v* d1 = pout + jb + j0;
        const i32x2v* d2 = pout + jb + j0 + 2;
        asm volatile("global_store_dwordx4 %0, %1, off sc0 sc1"
                     :: "v"(d1), "v"(o1) : "memory");
        asm volatile("global_store_dwordx4 %0, %1, off sc0 sc1"
                     :: "v"(d2), "v"(o2) : "memory");
      }
      if (b == NBLK - 1 && lane == 0) {
        float s16 = 0.f;
        #pragma unroll
        for (int p = 0; p < 8; ++p) s16 += part2[p];
        float r16 = em_lds[16] + m + __logf(s16);
        i32x2v o; o.x = __float_as_int(r16); o.y = tag;
        const i32x2v* dst = pout + 4096;
        asm volatile("global_store_dwordx2 %0, %1, off sc0 sc1"
                     :: "v"(dst), "v"(o) : "memory");
      }
    }
    __syncthreads();
  }
}

// termination: logsumexp_j(fs[j] + log_trans[j][0])
__global__ void __launch_bounds__(1024) hmm_final(
    const i32x2v* __restrict__ fsp, const float* __restrict__ log_trans,
    float* __restrict__ out)
{
  __shared__ float red[16];
  const int tid = threadIdx.x, lane = tid & 63, wid = tid >> 6;
  float va[5];
  float rmax = -3.4e38f;
  #pragma unroll
  for (int i = 0; i < 5; ++i) {
    int k = tid + i * 1024;
    va[i] = (k < S) ? (__int_as_float(fsp[k].x) + log_trans[(size_t)k * S]) : -3.4e38f;
    rmax = fmaxf(rmax, va[i]);
  }
  #pragma unroll
  for (int off = 32; off; off >>= 1) rmax = fmaxf(rmax, __shfl_xor(rmax, off, 64));
  if (lane == 0) red[wid] = rmax;
  __syncthreads();
  float m = red[0];
  #pragma unroll
  for (int i = 1; i < 16; ++i) m = fmaxf(m, red[i]);
  float s = 0.f;
  #pragma unroll
  for (int i = 0; i < 5; ++i) s += __expf(va[i] - m);
  #pragma unroll
  for (int off = 32; off; off >>= 1) s += __shfl_xor(s, off, 64);
  __syncthreads();
  if (lane == 0) red[wid] = s;
  __syncthreads();
  if (tid == 0) {
    float tot = 0.f;
    #pragma unroll
    for (int i = 0; i < 16; ++i) tot += red[i];
    out[0] = m + __logf(tot);
  }
}

extern "C" void kernel_launch(void* const* d_in, const int* in_sizes, int n_in,
                              void* d_out, int out_size, void* d_ws, size_t ws_size,
                              hipStream_t stream) {
  const float* log_pi    = (const float*)d_in[0];
  const float* log_trans = (const float*)d_in[1];
  const float* log_em    = (const float*)d_in[2];
  const int*   obvs      = (const int*)d_in[3];
  const int    T         = in_sizes[3];

  i32x2v* pairs = (i32x2v*)d_ws;                     // 2 * 4097 * 8 B
  hipMemsetAsync(pairs, 0, 2 * PAIRS * sizeof(i32x2v), stream);  // tags < 1: replay-safe

  hipLaunchKernelGGL(hmm_persist, dim3(NBLK), dim3(NTHR), 0, stream,
                     log_pi, log_trans, log_em, obvs, pairs, T);
  const i32x2v* fsT = pairs + (size_t)((T - 1) & 1) * PAIRS;
  hipLaunchKernelGGL(hmm_final, dim3(1), dim3(1024), 0, stream,
                     fsT, log_trans, (float*)d_out);
}